// Round 1
// baseline (1363.545 us; speedup 1.0000x reference)
//
#include <hip/hip_runtime.h>

// FactorizedSpectralConv2d on MI355X, round 0: correctness-first fused fp32 kernel.
// x: [B=32][I=64][M=128][N=128] f32; w0,w1: [64][64][32][2] f32; out: [32][64][128][128] f32.
//
// Each branch (axis A in {N (width), M (height)}):
//   Y[k,i,t]  = sum_d x[i, d@A, t] * e^{-2pi i k d/128}        (unnormalized fwd DFT, k<32)
//   Z[k,o,t]  = sum_i Y[k,i,t] * (w[i,o,k,0] + j w[i,o,k,1])   (complex channel mix)
//   out[o,d,t]= (1/128) * ( Zre[0] + sum_{k=1..31} 2*(Zre[k] cos - Zim[k] sin) )
// Note: irfft (pocketfft c2r) ignores the imag part of the DC bin -> Z0_im coefficient = 0.
// Width branch writes out; height branch accumulates (launched after on same stream).

#define NB   32
#define IC   64
#define OC   64
#define DLEN 128
#define KM   32
#define TBLK 4
#define NTH  256

__global__ __launch_bounds__(NTH) void spectral_branch(
    const float* __restrict__ x, const float* __restrict__ w,
    float* __restrict__ out, int strideD, int strideT, int accumulate)
{
    // Basis: Bf[2k][d] = cos(2pi k d/128), Bf[2k+1][d] = -sin(2pi k d/128)
    __shared__ float Bf[2 * KM][132];   // padded: rows 132 words -> bank offset 4/row
    __shared__ float xs[TBLK][132];     // current input channel tile [t][d]
    __shared__ float Yre[KM][TBLK];
    __shared__ float Yim[KM][TBLK];
    __shared__ float Zs[2 * KM][128];   // epilogue staging: half the (o,t) rows at a time

    const int tid  = threadIdx.x;
    const int blk  = blockIdx.x;
    const int b    = blk >> 5;          // 32 tiles per batch (128/TBLK)
    const int tile = blk & 31;
    const int xbase = b * (IC * DLEN * DLEN) + tile * TBLK * strideT;
    const int obase = xbase;            // identical geometry (OC == IC)

    // ---- init basis (once per block) ----
    for (int j = tid; j < 2 * KM * DLEN; j += NTH) {
        const int kp = j >> 7, d = j & 127;
        const int k  = kp >> 1;
        const int idx = (k * d) & 127;
        const float ang = 0.049087385212340517f * (float)idx;   // 2*pi/128
        Bf[kp][d] = (kp & 1) ? -sinf(ang) : cosf(ang);
    }

    float Zre[KM], Zim[KM];
#pragma unroll
    for (int k = 0; k < KM; ++k) { Zre[k] = 0.f; Zim[k] = 0.f; }

    const int o_mix  = tid >> 2;   // 0..63  (mix phase: thread owns (o, t))
    const int t_mix  = tid & 3;
    const int kp_dft = tid >> 2;   // 0..63  (DFT phase: thread owns (kpart, t))
    const int t_dft  = tid & 3;

    __syncthreads();

    // ================= main loop over input channels =================
    for (int i = 0; i < IC; ++i) {
        const float* xi = x + xbase + i * (DLEN * DLEN);
        if (strideD == 1) {                 // width: DFT axis contiguous
            for (int j = tid; j < TBLK * DLEN; j += NTH) {
                const int d = j & 127, t = j >> 7;
                xs[t][d] = xi[d + t * strideT];
            }
        } else {                            // height: tile axis contiguous
            for (int j = tid; j < TBLK * DLEN; j += NTH) {
                const int t = j & 3, d = j >> 2;
                xs[t][d] = xi[d * strideD + t];
            }
        }
        __syncthreads();

        // ---- forward DFT panel: Y[kp][t] = sum_d Bf[kp][d] * xs[t][d] ----
        {
            float acc = 0.f;
            const float* bro = &Bf[kp_dft][0];
            const float* xro = &xs[t_dft][0];
#pragma unroll 8
            for (int d = 0; d < DLEN; d += 4) {
                const float4 bv = *(const float4*)(bro + d);
                const float4 xv = *(const float4*)(xro + d);
                acc += bv.x * xv.x + bv.y * xv.y + bv.z * xv.z + bv.w * xv.w;
            }
            const int k = kp_dft >> 1;
            if (kp_dft & 1) Yim[k][t_dft] = acc; else Yre[k][t_dft] = acc;
        }
        __syncthreads();

        // ---- complex channel mix into registers ----
        {
            const float2* wrow = (const float2*)w + (i * OC + o_mix) * KM;
#pragma unroll
            for (int k = 0; k < KM; ++k) {
                const float  yr = Yre[k][t_mix];
                const float  yi = Yim[k][t_mix];
                const float2 wv = wrow[k];
                Zre[k] += yr * wv.x - yi * wv.y;
                Zim[k] += yr * wv.y + yi * wv.x;
            }
        }
        __syncthreads();   // protect Y (and xs) before next iteration overwrites
    }

    // ================= epilogue: inverse DFT =================
    const float s1 = 1.0f / 128.0f, s2 = 2.0f / 128.0f;

    for (int h = 0; h < 2; ++h) {      // two halves of o to keep Zs at 32 KB
        if ((o_mix >> 5) == h) {
            const int rw = ((o_mix & 31) << 2) | t_mix;   // row within half: 0..127
            Zs[0][rw] = Zre[0] * s1;
            Zs[1][rw] = 0.f;                               // irfft ignores DC imag
#pragma unroll
            for (int k = 1; k < KM; ++k) {
                Zs[2 * k][rw]     = Zre[k] * s2;
                Zs[2 * k + 1][rw] = Zim[k] * s2;
            }
        }
        __syncthreads();

        const int rg = tid & 31;            // rowgroup: rows rg*4..rg*4+3 (one o, t=0..3)
        const int o  = (h << 5) + rg;
        float* outo = out + obase + o * (DLEN * DLEN);

        for (int cg = tid >> 5; cg < 32; cg += 8) {   // colgroup: d = cg*4..cg*4+3
            float acc[4][4];
#pragma unroll
            for (int r = 0; r < 4; ++r)
#pragma unroll
                for (int c = 0; c < 4; ++c) acc[r][c] = 0.f;

#pragma unroll 4
            for (int kp = 0; kp < 2 * KM; ++kp) {
                const float4 zv = *(const float4*)&Zs[kp][rg * 4];
                const float4 bv = *(const float4*)&Bf[kp][cg * 4];
                acc[0][0] += zv.x * bv.x; acc[0][1] += zv.x * bv.y;
                acc[0][2] += zv.x * bv.z; acc[0][3] += zv.x * bv.w;
                acc[1][0] += zv.y * bv.x; acc[1][1] += zv.y * bv.y;
                acc[1][2] += zv.y * bv.z; acc[1][3] += zv.y * bv.w;
                acc[2][0] += zv.z * bv.x; acc[2][1] += zv.z * bv.y;
                acc[2][2] += zv.z * bv.z; acc[2][3] += zv.z * bv.w;
                acc[3][0] += zv.w * bv.x; acc[3][1] += zv.w * bv.y;
                acc[3][2] += zv.w * bv.z; acc[3][3] += zv.w * bv.w;
            }

            if (strideD == 1) {
                // rows r = t (stride 128), cols c = d contiguous -> float4 along c
#pragma unroll
                for (int r = 0; r < 4; ++r) {
                    float4 v = make_float4(acc[r][0], acc[r][1], acc[r][2], acc[r][3]);
                    float4* p = (float4*)(outo + r * strideT + cg * 4);
                    if (accumulate) {
                        const float4 old = *p;
                        v.x += old.x; v.y += old.y; v.z += old.z; v.w += old.w;
                    }
                    *p = v;
                }
            } else {
                // rows r = t contiguous -> float4 along r, one per col c
#pragma unroll
                for (int c = 0; c < 4; ++c) {
                    float4 v = make_float4(acc[0][c], acc[1][c], acc[2][c], acc[3][c]);
                    float4* p = (float4*)(outo + (cg * 4 + c) * strideD);
                    if (accumulate) {
                        const float4 old = *p;
                        v.x += old.x; v.y += old.y; v.z += old.z; v.w += old.w;
                    }
                    *p = v;
                }
            }
        }
        __syncthreads();   // Zs reused by next half
    }
}

extern "C" void kernel_launch(void* const* d_in, const int* in_sizes, int n_in,
                              void* d_out, int out_size, void* d_ws, size_t ws_size,
                              hipStream_t stream) {
    const float* x  = (const float*)d_in[0];
    const float* w0 = (const float*)d_in[1];
    const float* w1 = (const float*)d_in[2];
    float* out = (float*)d_out;

    dim3 grid(NB * (DLEN / TBLK));   // 1024 blocks
    dim3 block(NTH);

    // width branch (DFT along last axis): writes out
    spectral_branch<<<grid, block, 0, stream>>>(x, w0, out, /*strideD=*/1, /*strideT=*/128, /*acc=*/0);
    // height branch (DFT along M axis): accumulates
    spectral_branch<<<grid, block, 0, stream>>>(x, w1, out, /*strideD=*/128, /*strideT=*/1, /*acc=*/1);
}

// Round 2
// 789.261 us; speedup vs baseline: 1.7276x; 1.7276x over previous
//
#include <hip/hip_runtime.h>

// FactorizedSpectralConv2d, round 1: MFMA (f16 in / f32 acc) for forward+inverse DFT,
// v_dot2_f32_f16 VALU for the per-mode complex channel mix.
//
// Per branch (axis A): Y[kp,i,t] = DFT(x), Z[kp,o,t] = mode-mix(Y, W), out = iDFT(Z).
// kp = 2k+{re,im}, k < 32 modes, transform length 128, ortho norm folded as 1/128 into G,
// irfft drops the DC imaginary part -> G column kp==1 is zero.
//
// Block = (batch b, tile of 16 lines), 1024 threads = 16 waves. 8 chunks of 8 input channels.
// LDS: U region 36 KB (Xs fp16 staging, later overlaid by Zs) + Ys 20 KB = 56 KB.

typedef _Float16 half8  __attribute__((ext_vector_type(8)));
typedef _Float16 half2v __attribute__((ext_vector_type(2)));
typedef float    floatx4 __attribute__((ext_vector_type(4)));

#define TWO_PI_OVER_128 0.049087385212340517f

__device__ __forceinline__ unsigned int packh2(float a, float b) {
    half2v h; h[0] = (_Float16)a; h[1] = (_Float16)b;
    return __builtin_bit_cast(unsigned int, h);
}
__device__ __forceinline__ half2v ash2(unsigned int u) {
    return __builtin_bit_cast(half2v, u);
}
__device__ __forceinline__ half8 ash8(uint4 u) {
    return __builtin_bit_cast(half8, u);
}

#if __has_builtin(__builtin_amdgcn_fdot2)
__device__ __forceinline__ float fdot2f(unsigned int y, unsigned int w, float c) {
    return __builtin_amdgcn_fdot2(ash2(y), ash2(w), c, false);
}
#else
__device__ __forceinline__ float fdot2f(unsigned int y, unsigned int w, float c) {
    half2v yh = ash2(y), wh = ash2(w);
    return c + (float)yh[0] * (float)wh[0] + (float)yh[1] * (float)wh[1];
}
#endif

// BR=0: width branch (DFT axis contiguous), writes out.
// BR=1: height branch (DFT axis strided by 128), accumulates into out.
template<int BR>
__global__ __launch_bounds__(1024, 4) void spectral(const float* __restrict__ x,
                                                    const float* __restrict__ wt,
                                                    float* __restrict__ out)
{
    // U region: Xs [128 cols][136 fp16] = 34816 B  OR  Zs [256 cols][36 uint] = 36864 B
    __shared__ uint4 Ubuf[36864 / 16];
    __shared__ unsigned int Ys[8 * 32 * 20];          // [i][k][t] packed half2(yre,yim), 20480 B

    unsigned short* Xs = (unsigned short*)Ubuf;
    unsigned int*   Zs = (unsigned int*)Ubuf;

    const int tid  = threadIdx.x;
    const int wv   = tid >> 6;
    const int mrow = tid & 15;        // lane & 15
    const int quad = (tid >> 4) & 3;  // (lane >> 4)
    const int bx   = blockIdx.x;
    const int b    = bx >> 3;
    const int tile = bx & 7;

    const long xb = (long)b * 1048576 + (BR == 0 ? tile * 2048 : tile * 16);
    const long ob = xb;  // same geometry (OC == IC)

    // ---- stage-1 A fragments: F[kp][d], kp-tile fixed per wave, computed in regs ----
    const int kptile = wv & 3;
    half8 Ff[4];
#pragma unroll
    for (int s = 0; s < 4; ++s)
#pragma unroll
        for (int j = 0; j < 8; ++j) {
            int d  = s * 32 + quad * 8 + j;
            int kp = kptile * 16 + mrow;
            int k  = kp >> 1;
            float ang = TWO_PI_OVER_128 * (float)((k * d) & 127);
            float v = (kp & 1) ? -sinf(ang) : cosf(ang);
            Ff[s][j] = (_Float16)v;
        }

    // ---- mix ownership: thread = (o, ks) owns k = {2ks, 2ks+1} for all 16 t ----
    const int o_mix = tid >> 4;
    const int ks    = tid & 15;
    const int wf4_off0 = o_mix * 16 + ks;
    const float4* wf4 = (const float4*)wt;

    float Zr[2][16], Zi[2][16];
#pragma unroll
    for (int kk = 0; kk < 2; ++kk)
#pragma unroll
        for (int t = 0; t < 16; ++t) { Zr[kk][t] = 0.f; Zi[kk][t] = 0.f; }

    // ================= chunk loop: 8 chunks x 8 input channels =================
    for (int c = 0; c < 8; ++c) {
        __syncthreads();   // U free (prev mix done), Ys free

        // ---------- global -> Xs[col = i*16+t][d] fp16 ----------
        if (BR == 0) {
#pragma unroll
            for (int p = 0; p < 4; ++p) {
                int idx = p * 1024 + tid;
                int col = idx >> 5, dg = idx & 31;
                int i = col >> 4, t = col & 15;
                const float4 v = *(const float4*)(x + xb + (long)(c * 8 + i) * 16384 + t * 128 + dg * 4);
                uint2 u = make_uint2(packh2(v.x, v.y), packh2(v.z, v.w));
                *(uint2*)&Xs[col * 136 + dg * 4] = u;
            }
        } else {
#pragma unroll
            for (int p = 0; p < 4; ++p) {
                int i  = (tid >> 9) + p * 2;
                int d  = (tid >> 2) & 127;
                int tq = (tid & 3) * 4;
                const float4 v = *(const float4*)(x + xb + (long)(c * 8 + i) * 16384 + d * 128 + tq);
                int colb = i * 16 + tq;
                Xs[(colb + 0) * 136 + d] = __builtin_bit_cast(unsigned short, (_Float16)v.x);
                Xs[(colb + 1) * 136 + d] = __builtin_bit_cast(unsigned short, (_Float16)v.y);
                Xs[(colb + 2) * 136 + d] = __builtin_bit_cast(unsigned short, (_Float16)v.z);
                Xs[(colb + 3) * 136 + d] = __builtin_bit_cast(unsigned short, (_Float16)v.w);
            }
        }
        __syncthreads();   // Xs ready

        // ---------- stage 1: Y = F x X, write Ys packed ----------
#pragma unroll
        for (int cc = 0; cc < 2; ++cc) {
            int i = (wv >> 2) * 2 + cc;
            floatx4 acc = {0.f, 0.f, 0.f, 0.f};
#pragma unroll
            for (int s = 0; s < 4; ++s) {
                uint4 bv = *(const uint4*)&Xs[(i * 16 + mrow) * 136 + s * 32 + quad * 8];
                acc = __builtin_amdgcn_mfma_f32_16x16x32_f16(Ff[s], ash8(bv), acc, 0, 0, 0);
            }
            // C layout: col = lane&15 = t, row = quad*4 + r -> kp consecutive
            int k0 = (kptile * 16 + quad * 4) >> 1;
            Ys[(i * 32 + k0    ) * 20 + mrow] = packh2(acc[0], acc[1]);
            Ys[(i * 32 + k0 + 1) * 20 + mrow] = packh2(acc[2], acc[3]);
        }
        __syncthreads();   // Ys ready, Xs reads done

        // ---------- mix: Z[k,o,t] += W_k[o,i] * Y[k,i,t] (complex) ----------
#pragma unroll
        for (int ih = 0; ih < 8; ih += 4) {
            float4 wq[4];
#pragma unroll
            for (int ii = 0; ii < 4; ++ii)
                wq[ii] = wf4[(c * 8 + ih + ii) * 1024 + wf4_off0];
#pragma unroll
            for (int ii = 0; ii < 4; ++ii) {
                int i = ih + ii;
#pragma unroll
                for (int kk = 0; kk < 2; ++kk) {
                    int k = ks * 2 + kk;
                    float wre = kk ? wq[ii].z : wq[ii].x;
                    float wim = kk ? wq[ii].w : wq[ii].y;
                    unsigned int wa = packh2(wre, -wim);  // dot2(y, wa) = yre*wre - yim*wim
                    unsigned int wb = packh2(wim,  wre);  // dot2(y, wb) = yre*wim + yim*wre
#pragma unroll
                    for (int tq = 0; tq < 4; ++tq) {
                        uint4 yv = *(const uint4*)&Ys[(i * 32 + k) * 20 + tq * 4];
                        Zr[kk][tq * 4 + 0] = fdot2f(yv.x, wa, Zr[kk][tq * 4 + 0]);
                        Zi[kk][tq * 4 + 0] = fdot2f(yv.x, wb, Zi[kk][tq * 4 + 0]);
                        Zr[kk][tq * 4 + 1] = fdot2f(yv.y, wa, Zr[kk][tq * 4 + 1]);
                        Zi[kk][tq * 4 + 1] = fdot2f(yv.y, wb, Zi[kk][tq * 4 + 1]);
                        Zr[kk][tq * 4 + 2] = fdot2f(yv.z, wa, Zr[kk][tq * 4 + 2]);
                        Zi[kk][tq * 4 + 2] = fdot2f(yv.z, wb, Zi[kk][tq * 4 + 2]);
                        Zr[kk][tq * 4 + 3] = fdot2f(yv.w, wa, Zr[kk][tq * 4 + 3]);
                        Zi[kk][tq * 4 + 3] = fdot2f(yv.w, wb, Zi[kk][tq * 4 + 3]);
                    }
                }
            }
        }
    }

    // ================= stage 3: out = G x Z, quarter of o at a time =================
    const int dt  = wv & 7;
    const int ctb = (wv >> 3) * 8;
    const int dp  = dt * 16 + mrow;
    half8 Gf[2];
#pragma unroll
    for (int s = 0; s < 2; ++s)
#pragma unroll
        for (int j = 0; j < 8; ++j) {
            int kp = s * 32 + quad * 8 + j;
            int k  = kp >> 1;
            float ang = TWO_PI_OVER_128 * (float)((k * dp) & 127);
            float v;
            if (kp == 0)      v = 1.f / 128.f;
            else if (kp == 1) v = 0.f;                       // irfft drops DC imag
            else v = (kp & 1) ? -(2.f / 128.f) * sinf(ang) : (2.f / 128.f) * cosf(ang);
            Gf[s][j] = (_Float16)v;
        }

    for (int q = 0; q < 4; ++q) {
        __syncthreads();   // prev quarter's Zs reads (or chunk-7 Xs reads) done
        if ((o_mix >> 4) == q) {
            int col0 = (o_mix & 15) * 16;
#pragma unroll
            for (int kk = 0; kk < 2; ++kk)
#pragma unroll
                for (int t = 0; t < 16; ++t)
                    Zs[(col0 + t) * 36 + ks * 2 + kk] = packh2(Zr[kk][t], Zi[kk][t]);
        }
        __syncthreads();   // Zs ready

#pragma unroll
        for (int cc = 0; cc < 8; ++cc) {
            int ct = ctb + cc;
            floatx4 acc = {0.f, 0.f, 0.f, 0.f};
#pragma unroll
            for (int s = 0; s < 2; ++s) {
                uint4 zv = *(const uint4*)&Zs[(ct * 16 + mrow) * 36 + s * 16 + quad * 4];
                acc = __builtin_amdgcn_mfma_f32_16x16x32_f16(Gf[s], ash8(zv), acc, 0, 0, 0);
            }
            int oo = q * 16 + ct;      // output channel
            int t  = mrow;             // line within tile
            int db = dt * 16 + quad * 4;
            if (BR == 0) {
                float4 v = make_float4(acc[0], acc[1], acc[2], acc[3]);
                *(float4*)(out + ob + (long)oo * 16384 + t * 128 + db) = v;
            } else {
                float* p = out + ob + (long)oo * 16384 + (long)db * 128 + t;
                p[0]   += acc[0];
                p[128] += acc[1];
                p[256] += acc[2];
                p[384] += acc[3];
            }
        }
    }
}

extern "C" void kernel_launch(void* const* d_in, const int* in_sizes, int n_in,
                              void* d_out, int out_size, void* d_ws, size_t ws_size,
                              hipStream_t stream) {
    const float* x  = (const float*)d_in[0];
    const float* w0 = (const float*)d_in[1];
    const float* w1 = (const float*)d_in[2];
    float* out = (float*)d_out;

    dim3 grid(256);    // 32 batches x 8 line-tiles
    dim3 block(1024);

    spectral<0><<<grid, block, 0, stream>>>(x, w0, out);   // width branch: writes out
    spectral<1><<<grid, block, 0, stream>>>(x, w1, out);   // height branch: accumulates
}